// Round 16
// baseline (274.993 us; speedup 1.0000x reference)
//
#include <hip/hip_runtime.h>

// Problem constants (S, B, E, H) = (2048, 2, 1024, 16), D = 64
#define SEQ   2048
#define BATCH 2
#define NH    16
#define HD    64
#define EMB   1024

// Q is pre-scaled by log2(e)/8 at the QKV-projection epilogue, so both
// attention kernels compute exp(score/8) as exp2(S) with no per-element mul.
#define QSCALE 0.18033688011112042f

using bf16x8 = __attribute__((ext_vector_type(8))) short;  // 8 bf16 (4 VGPRs)
using f32x4  = __attribute__((ext_vector_type(4))) float;
using f32x16 = __attribute__((ext_vector_type(16))) float;

__device__ __forceinline__ unsigned short f2bf(float f) {
  unsigned int u = __float_as_uint(f);
  u += 0x7FFFu + ((u >> 16) & 1u);          // RNE
  return (unsigned short)(u >> 16);
}
__device__ __forceinline__ unsigned pk_bf16(float lo, float hi) {
  unsigned r;
  asm("v_cvt_pk_bf16_f32 %0, %1, %2" : "=v"(r) : "v"(lo), "v"(hi));
  return r;
}
// async global->LDS, 16B per lane; LDS dest = uniform base + lane*16
__device__ __forceinline__ void gload16(const void* g, void* l) {
  __builtin_amdgcn_global_load_lds(
      (const __attribute__((address_space(1))) unsigned int*)g,
      (__attribute__((address_space(3))) unsigned int*)l, 16, 0, 0);
}

// ---------------------------------------------------------------- cvt f32->bf16 (fused x, w_qkv, w_out)
__global__ __launch_bounds__(256) void cvt3_f32_bf16(
    const float* __restrict__ a, int na4,
    const float* __restrict__ b, int nb4,
    const float* __restrict__ c, int nc4,
    unsigned short* __restrict__ oa,
    unsigned short* __restrict__ ob,
    unsigned short* __restrict__ oc) {
  int i = blockIdx.x * 256 + threadIdx.x;
  const float* src;
  unsigned short* dst;
  int j = i;
  if (j < na4) { src = a; dst = oa; }
  else if ((j -= na4) < nb4) { src = b; dst = ob; }
  else { j -= nb4; if (j >= nc4) return; src = c; dst = oc; }
  float4 v = reinterpret_cast<const float4*>(src)[j];
  ushort4 o;
  o.x = f2bf(v.x); o.y = f2bf(v.y); o.z = f2bf(v.z); o.w = f2bf(v.w);
  reinterpret_cast<ushort4*>(dst)[j] = o;
}

// ---------------------------------------------------------------- GEMM C = A * B^T (+bias)
// A[M][K] bf16, B[N][K] bf16, fp32 accumulate. 128x128 tile, BK=64, 4 waves (2x2).
// Staging via global_load_lds dwordx4: linear LDS dest, pre-swizzled global src
// (slot [r][cc] holds global chunk cc^(r&7); readers use [r][j^(r&7)]).
// EPI==0: C fp32 row-major [M][N]
// EPI==1: scatter QKV -> Q (x QSCALE) / K bf16 [B][H][S][D], V -> V^T bf16 [B][H][D][S]
template <int EPI>
__global__ __launch_bounds__(256) void gemm_bt(
    const unsigned short* __restrict__ A,
    const unsigned short* __restrict__ B,
    const float* __restrict__ bias,
    float* __restrict__ Cf,
    unsigned short* __restrict__ Qb,
    unsigned short* __restrict__ Kb,
    unsigned short* __restrict__ VTb,
    int M, int N, int K) {
  __shared__ int4 As[128][8];
  __shared__ int4 Bs[128][8];
  const int tid = threadIdx.x;
  const int wid = tid >> 6, lane = tid & 63;
  const int wm = wid >> 1, wn = wid & 1;
  const int lg = lane >> 4, lr = lane & 15;
  const int lr8 = lane >> 3;
  const int lc8 = (lane & 7) ^ lr8;
  const int row0 = blockIdx.x * 128, col0 = blockIdx.y * 128;
  f32x4 acc[4][4] = {};
  for (int k0 = 0; k0 < K; k0 += 64) {
#pragma unroll
    for (int i = 0; i < 4; i++) {
      const int rb = wid * 32 + i * 8;
      gload16(&A[(size_t)(row0 + rb + lr8) * K + k0 + lc8 * 8], &As[rb][0]);
      gload16(&B[(size_t)(col0 + rb + lr8) * K + k0 + lc8 * 8], &Bs[rb][0]);
    }
    __syncthreads();
#pragma unroll
    for (int ks = 0; ks < 2; ks++) {
      bf16x8 af[4], bfr[4];
#pragma unroll
      for (int mi = 0; mi < 4; mi++) {
        int r = wm * 64 + mi * 16 + lr;
        af[mi] = *reinterpret_cast<const bf16x8*>(&As[r][(ks * 4 + lg) ^ (r & 7)]);
      }
#pragma unroll
      for (int ni = 0; ni < 4; ni++) {
        int r = wn * 64 + ni * 16 + lr;
        bfr[ni] = *reinterpret_cast<const bf16x8*>(&Bs[r][(ks * 4 + lg) ^ (r & 7)]);
      }
#pragma unroll
      for (int mi = 0; mi < 4; mi++)
#pragma unroll
        for (int ni = 0; ni < 4; ni++)
          acc[mi][ni] = __builtin_amdgcn_mfma_f32_16x16x32_bf16(af[mi], bfr[ni], acc[mi][ni], 0, 0, 0);
    }
    __syncthreads();
  }
  // epilogue: C/D layout col=lane&15, row=(lane>>4)*4+r  [m89-verified]
#pragma unroll
  for (int mi = 0; mi < 4; mi++)
#pragma unroll
    for (int ni = 0; ni < 4; ni++) {
      const int row_b = row0 + wm * 64 + mi * 16 + lg * 4;   // even
      const int col = col0 + wn * 64 + ni * 16 + lr;
      const float bs = bias[col];
      float v0 = acc[mi][ni][0] + bs;
      float v1 = acc[mi][ni][1] + bs;
      float v2 = acc[mi][ni][2] + bs;
      float v3 = acc[mi][ni][3] + bs;
      if (EPI == 0) {
        Cf[(size_t)(row_b + 0) * N + col] = v0;
        Cf[(size_t)(row_b + 1) * N + col] = v1;
        Cf[(size_t)(row_b + 2) * N + col] = v2;
        Cf[(size_t)(row_b + 3) * N + col] = v3;
      } else {
        const int which = col >> 10, rr = col & 1023;
        const int hh = rr >> 6, d = rr & 63;
        if (which == 2) {
          // V^T [b][h][d][s]; rows row_b+r = s*2+b -> b=r&1, s=s0+(r>>1)
          const int s0 = row_b >> 1;
          ushort2 p0; p0.x = f2bf(v0); p0.y = f2bf(v2);   // b=0
          ushort2 p1; p1.x = f2bf(v1); p1.y = f2bf(v3);   // b=1
          *reinterpret_cast<ushort2*>(&VTb[((size_t)((0 * NH + hh) * HD + d)) * SEQ + s0]) = p0;
          *reinterpret_cast<ushort2*>(&VTb[((size_t)((1 * NH + hh) * HD + d)) * SEQ + s0]) = p1;
        } else {
          unsigned short* dst = which == 0 ? Qb : Kb;
          const float sc = (which == 0) ? QSCALE : 1.0f;
          float vv[4] = {v0 * sc, v1 * sc, v2 * sc, v3 * sc};
#pragma unroll
          for (int r = 0; r < 4; r++) {
            int s = (row_b + r) >> 1, bb = r & 1;
            dst[(size_t)((bb * NH + hh) * SEQ + s) * HD + d] = f2bf(vv[r]);
          }
        }
      }
    }
}

// ---------------------------------------------------------------- attention pass 1 (v8, frozen)
__global__ __launch_bounds__(256, 2) void attn1(
    const unsigned short* __restrict__ Qb,
    const unsigned short* __restrict__ Kb,
    const unsigned short* __restrict__ VTb,
    unsigned short* __restrict__ attn_bf,
    float* __restrict__ lbuf) {
  __shared__ int4 Kt[2][64][8];
  __shared__ int4 Vt[2][64][8];
  const int tid = threadIdx.x;
  const int wid = tid >> 6, lane = tid & 63;
  const int l31 = lane & 31, lhi = lane >> 5;
  const int lr8 = lane >> 3;
  const int L = blockIdx.x;
  const int v = (L & 7) * 64 + (L >> 3);
  const int bh = v >> 4, stile = v & 15;
  const int b = bh >> 4, h = bh & 15;
  const int s0 = stile * 128 + wid * 32;
  const unsigned short* Qg = Qb + (size_t)bh * SEQ * HD;
  const unsigned short* Kg = Kb + (size_t)bh * SEQ * HD;
  const unsigned short* VTg = VTb + (size_t)bh * HD * SEQ;

  bf16x8 qf[4];
#pragma unroll
  for (int ks = 0; ks < 4; ks++)
    qf[ks] = *reinterpret_cast<const bf16x8*>(Qg + (size_t)(s0 + l31) * HD + ks * 16 + lhi * 8);

  auto stage = [&](int tg, int buf) {
#pragma unroll
    for (int i = 0; i < 2; i++) {
      const int rb = wid * 16 + i * 8;
      const int lc = (lane & 7) ^ (((rb >> 2) + lhi) & 7);
      gload16(Kg + (size_t)(tg * 64 + rb + lr8) * HD + lc * 8, &Kt[buf][rb][0]);
      gload16(VTg + (size_t)(rb + lr8) * SEQ + tg * 64 + lc * 8, &Vt[buf][rb][0]);
    }
  };
  const int swv = l31 >> 2;

  const f32x16 fz = {};
  f32x16 o[2] = {};
  f32x16 osum = {};
  const short one_bf = (short)0x3F80;
  const bf16x8 vone = {one_bf, one_bf, one_bf, one_bf, one_bf, one_bf, one_bf, one_bf};
  bf16x8 paq[4];
  bf16x8 vfr[2][4];

  auto qk = [&](int cur, f32x16 st[2]) {
#pragma unroll
    for (int ti = 0; ti < 2; ti++) {
      const int row = ti * 32 + l31;
      bf16x8 kf = *reinterpret_cast<const bf16x8*>(&Kt[cur][row][lhi ^ swv]);
      st[ti] = __builtin_amdgcn_mfma_f32_32x32x16_bf16(kf, qf[0], fz, 0, 0, 0);
    }
#pragma unroll
    for (int ks = 1; ks < 4; ks++)
#pragma unroll
      for (int ti = 0; ti < 2; ti++) {
        const int row = ti * 32 + l31;
        bf16x8 kf = *reinterpret_cast<const bf16x8*>(&Kt[cur][row][(ks * 2 + lhi) ^ swv]);
        st[ti] = __builtin_amdgcn_mfma_f32_32x32x16_bf16(kf, qf[ks], st[ti], 0, 0, 0);
      }
  };
  auto softpack = [&](const f32x16 st[2]) {
    float p[32];
#pragma unroll
    for (int ti = 0; ti < 2; ti++)
#pragma unroll
      for (int r = 0; r < 16; r++)
        p[ti * 16 + r] = __builtin_amdgcn_exp2f(st[ti][r]);
#pragma unroll
    for (int c = 0; c < 4; c++) {
      const int ti = c >> 1, cc = c & 1;
      const int pb = ti * 16 + cc * 8;
      unsigned w0 = pk_bf16(p[pb + 0], p[pb + 1]);
      unsigned w1 = pk_bf16(p[pb + 2], p[pb + 3]);
      unsigned w2 = pk_bf16(p[pb + 4], p[pb + 5]);
      unsigned w3 = pk_bf16(p[pb + 6], p[pb + 7]);
      asm volatile("v_permlane32_swap_b32 %0, %1" : "+v"(w0), "+v"(w2));
      asm volatile("v_permlane32_swap_b32 %0, %1" : "+v"(w1), "+v"(w3));
      union { unsigned u[4]; bf16x8 v; } pa;
      pa.u[0] = w0; pa.u[1] = w1; pa.u[2] = w2; pa.u[3] = w3;
      paq[c] = pa.v;
    }
  };
  auto loadv = [&](int cur) {
#pragma unroll
    for (int dt = 0; dt < 2; dt++)
#pragma unroll
      for (int c = 0; c < 4; c++) {
        const int row = dt * 32 + l31;
        vfr[dt][c] = *reinterpret_cast<const bf16x8*>(&Vt[cur][row][(c * 2 + lhi) ^ swv]);
      }
  };

  stage(0, 0);
  __syncthreads();

  {
    stage(1, 1);
    f32x16 st[2];
    __builtin_amdgcn_s_setprio(1);
    qk(0, st);
    __builtin_amdgcn_s_setprio(0);
    softpack(st);
    loadv(0);
    __syncthreads();
  }

  for (int t = 1; t < 32; t++) {
    const int cur = t & 1;
    if (t + 1 < 32) stage(t + 1, cur ^ 1);
    f32x16 st[2];
    __builtin_amdgcn_s_setprio(1);
#pragma unroll
    for (int c = 0; c < 4; c++) {
#pragma unroll
      for (int dt = 0; dt < 2; dt++)
        o[dt] = __builtin_amdgcn_mfma_f32_32x32x16_bf16(paq[c], vfr[dt][c], o[dt], 0, 0, 0);
      osum = __builtin_amdgcn_mfma_f32_32x32x16_bf16(paq[c], vone, osum, 0, 0, 0);
    }
    qk(cur, st);
    __builtin_amdgcn_s_setprio(0);
    softpack(st);
    loadv(cur);
    __syncthreads();
  }
#pragma unroll
  for (int c = 0; c < 4; c++) {
#pragma unroll
    for (int dt = 0; dt < 2; dt++)
      o[dt] = __builtin_amdgcn_mfma_f32_32x32x16_bf16(paq[c], vfr[dt][c], o[dt], 0, 0, 0);
    osum = __builtin_amdgcn_mfma_f32_32x32x16_bf16(paq[c], vone, osum, 0, 0, 0);
  }

  if (l31 == 0) {
#pragma unroll
    for (int r = 0; r < 16; r++)
      lbuf[(size_t)bh * SEQ + s0 + (r & 3) + 8 * (r >> 2) + 4 * lhi] = osum[r];
  }

#pragma unroll
  for (int r = 0; r < 16; r++) {
    float inv = __builtin_amdgcn_rcpf(osum[r]);
    const int s = s0 + (r & 3) + 8 * (r >> 2) + 4 * lhi;
#pragma unroll
    for (int dt = 0; dt < 2; dt++) {
      float ov = o[dt][r] * inv;
      attn_bf[((size_t)s * BATCH + b) * EMB + h * HD + dt * 32 + l31] = f2bf(ov);
    }
  }
}

// ---------------------------------------------------------------- attention pass 2 (v10)
// v8 barrier structure (2 heads per barrier) with Q moved from LDS to ping-pong
// REGISTER fragments (prefetched one head-pair ahead; R8-verified access).
// LDS shrinks 53 -> 36 KB => 3-4 blocks/CU at NATURAL register allocation
// (no waves/EU bound: forcing one spilled in R14).
__global__ __launch_bounds__(256, 2) void attn2(
    const unsigned short* __restrict__ Qb,
    const unsigned short* __restrict__ Kb,
    const float* __restrict__ lbuf,
    float* __restrict__ avg_out) {
  const int b = blockIdx.z;
  const int s0 = blockIdx.y * 64;
  const int tc0 = blockIdx.x * 256;
  __shared__ int4 Ks[2][2][64][8];   // 32 KB  [dbuf][head-of-pair]
  __shared__ float lls[NH][64];      // 4 KB   1/(NH*l)
  const int tid = threadIdx.x;
  const int wid = tid >> 6, lane = tid & 63;
  const int wm = wid >> 1, wn = wid & 1;
  const int lg = lane >> 4, lr = lane & 15;
  const int lr8 = lane >> 3;
  const int lc8 = (lane & 7) ^ lr8;

  for (int i = tid; i < NH * 64; i += 256) {
    int hh = i >> 6, r = i & 63;
    lls[hh][r] = 1.0f / ((float)NH * lbuf[(b * NH + hh) * SEQ + s0 + r]);
  }

  const size_t bh0 = (size_t)(b * NH) * SEQ;

  auto stageK = [&](const unsigned short* src, int buf, int hsel) {
#pragma unroll
    for (int i = 0; i < 2; i++) {
      const int rb = wid * 16 + i * 8;
      gload16(src + (size_t)(rb + lr8) * HD + lc8 * 8, &Ks[buf][hsel][rb][0]);
    }
  };
  // Q fragments direct from global (same elements the old LDS read produced):
  // row = s0 + wm*32 + mi*16 + lr, col = ks*32 + lg*8
  auto loadQ = [&](int h0, bf16x8 (&af)[2][2][2]) {
#pragma unroll
    for (int hh = 0; hh < 2; hh++) {
      const unsigned short* Qgh = Qb + (bh0 + (size_t)(h0 + hh) * SEQ) * HD;
#pragma unroll
      for (int mi = 0; mi < 2; mi++)
#pragma unroll
        for (int ks = 0; ks < 2; ks++)
          af[hh][mi][ks] = *reinterpret_cast<const bf16x8*>(
              Qgh + (size_t)(s0 + wm * 32 + mi * 16 + lr) * HD + ks * 32 + lg * 8);
    }
  };

  bf16x8 afA[2][2][2], afB[2][2][2];
  loadQ(0, afA);
  stageK(Kb + (bh0 + tc0) * HD, 0, 0);
  stageK(Kb + (bh0 + SEQ + tc0) * HD, 0, 1);
  __syncthreads();

  const f32x4 fz4 = {};
  f32x4 avg[4][2][2] = {};

  auto hiter = [&](int hp, bf16x8 (&afc)[2][2][2], bf16x8 (&afn)[2][2][2]) {
    const int h0 = 2 * hp, h1 = h0 + 1;
    if (hp + 1 < NH / 2) loadQ(h0 + 2, afn);   // T14: next pair's Q in flight
    float linv[2][2][4];
#pragma unroll
    for (int hh = 0; hh < 2; hh++)
#pragma unroll
      for (int mi = 0; mi < 2; mi++)
#pragma unroll
        for (int r = 0; r < 4; r++)
          linv[hh][mi][r] = lls[h0 + hh][wm * 32 + mi * 16 + lg * 4 + r];

    const unsigned short* Kg0 = Kb + (bh0 + (size_t)h0 * SEQ + tc0) * HD;
    const unsigned short* Kg1 = Kb + (bh0 + (size_t)h1 * SEQ + tc0) * HD;

    for (int t0 = 0; t0 < 4; t0++) {
      const int cur = t0 & 1;
      if (t0 < 3) {
        stageK(Kg0 + (size_t)(t0 + 1) * 64 * HD, cur ^ 1, 0);
        stageK(Kg1 + (size_t)(t0 + 1) * 64 * HD, cur ^ 1, 1);
      } else if (hp + 1 < NH / 2) {
        stageK(Kb + (bh0 + (size_t)(h0 + 2) * SEQ + tc0) * HD, cur ^ 1, 0);
        stageK(Kb + (bh0 + (size_t)(h1 + 2) * SEQ + tc0) * HD, cur ^ 1, 1);
      }
      f32x4 sacc[2][2][2];   // [head][mi][ni]
      __builtin_amdgcn_s_setprio(1);
#pragma unroll
      for (int hh = 0; hh < 2; hh++)
#pragma unroll
        for (int ks = 0; ks < 2; ks++) {
          bf16x8 bk[2];
#pragma unroll
          for (int ni = 0; ni < 2; ni++) {
            int rk = wn * 32 + ni * 16 + lr;
            bk[ni] = *reinterpret_cast<const bf16x8*>(&Ks[cur][hh][rk][(ks * 4 + lg) ^ (rk & 7)]);
          }
#pragma unroll
          for (int mi = 0; mi < 2; mi++)
#pragma unroll
            for (int ni = 0; ni < 2; ni++)
              sacc[hh][mi][ni] = __builtin_amdgcn_mfma_f32_16x16x32_bf16(
                  afc[hh][mi][ks], bk[ni], ks == 0 ? fz4 : sacc[hh][mi][ni], 0, 0, 0);
        }
      __builtin_amdgcn_s_setprio(0);
#pragma unroll
      for (int hh = 0; hh < 2; hh++)
#pragma unroll
        for (int mi = 0; mi < 2; mi++)
#pragma unroll
          for (int ni = 0; ni < 2; ni++)
#pragma unroll
            for (int r = 0; r < 4; r++)
              avg[t0][mi][ni][r] += __builtin_amdgcn_exp2f(sacc[hh][mi][ni][r]) * linv[hh][mi][r];
      __syncthreads();
    }
  };

#pragma unroll 1
  for (int hp = 0; hp < NH / 2; hp += 2) {
    hiter(hp, afA, afB);
    hiter(hp + 1, afB, afA);
  }

#pragma unroll
  for (int t0 = 0; t0 < 4; t0++)
#pragma unroll
    for (int mi = 0; mi < 2; mi++)
#pragma unroll
      for (int ni = 0; ni < 2; ni++)
#pragma unroll
        for (int r = 0; r < 4; r++) {
          int s = s0 + wm * 32 + mi * 16 + lg * 4 + r;
          int t = tc0 + t0 * 64 + wn * 32 + ni * 16 + lr;
          avg_out[((size_t)b * SEQ + s) * SEQ + t] = avg[t0][mi][ni][r];
        }
}

// ---------------------------------------------------------------- launch
extern "C" void kernel_launch(void* const* d_in, const int* in_sizes, int n_in,
                              void* d_out, int out_size, void* d_ws, size_t ws_size,
                              hipStream_t stream) {
  const float* x     = (const float*)d_in[0];   // [S,B,E]
  const float* w_qkv = (const float*)d_in[1];   // [3E,E]
  const float* b_qkv = (const float*)d_in[2];   // [3E]
  const float* w_out = (const float*)d_in[3];   // [E,E]
  const float* b_out = (const float*)d_in[4];   // [E]
  float* out = (float*)d_out;                         // [S,B,E] fp32
  float* avg = out + (size_t)SEQ * BATCH * EMB;       // [B,S,S] fp32

  char* ws = (char*)d_ws;
  size_t off = 0;
  unsigned short* x_bf    = (unsigned short*)(ws + off); off += (size_t)SEQ * BATCH * EMB * 2;       // 8 MB
  unsigned short* wqkv_bf = (unsigned short*)(ws + off); off += (size_t)3 * EMB * EMB * 2;           // 6 MB
  unsigned short* wout_bf = (unsigned short*)(ws + off); off += (size_t)EMB * EMB * 2;               // 2 MB
  unsigned short* Qbuf    = (unsigned short*)(ws + off); off += (size_t)BATCH * NH * SEQ * HD * 2;   // 8 MB
  unsigned short* Kbuf    = (unsigned short*)(ws + off); off += (size_t)BATCH * NH * SEQ * HD * 2;   // 8 MB
  unsigned short* VTbuf   = (unsigned short*)(ws + off); off += (size_t)BATCH * NH * HD * SEQ * 2;   // 8 MB
  unsigned short* attn_bf = (unsigned short*)(ws + off); off += (size_t)SEQ * BATCH * EMB * 2;       // 8 MB
  float*          lbuf    = (float*)(ws + off);          off += (size_t)BATCH * NH * SEQ * 4;        // 256 KB

  // 1) convert inputs to bf16 (single fused kernel)
  {
    const int na4 = SEQ * BATCH * EMB / 4;
    const int nb4 = 3 * EMB * EMB / 4;
    const int nc4 = EMB * EMB / 4;
    const int nblk = (na4 + nb4 + nc4 + 255) / 256;
    cvt3_f32_bf16<<<nblk, 256, 0, stream>>>(x, na4, w_qkv, nb4, w_out, nc4,
                                            x_bf, wqkv_bf, wout_bf);
  }

  // 2) QKV projection, scatter to Q (pre-scaled) / K [B][H][S][D] + V^T [B][H][D][S]
  gemm_bt<1><<<dim3(SEQ * BATCH / 128, 3 * EMB / 128), 256, 0, stream>>>(
      x_bf, wqkv_bf, b_qkv, nullptr, Qbuf, Kbuf, VTbuf, SEQ * BATCH, 3 * EMB, EMB);

  // 3) attention core (v8, frozen)
  attn1<<<512, 256, 0, stream>>>(Qbuf, Kbuf, VTbuf, attn_bf, lbuf);

  // 4) attention average over heads (v10: Q in registers, 36 KB LDS)
  attn2<<<dim3(SEQ / 256, SEQ / 64, BATCH), 256, 0, stream>>>(Qbuf, Kbuf, lbuf, avg);

  // 5) output projection -> d_out
  gemm_bt<0><<<dim3(SEQ * BATCH / 128, EMB / 128), 256, 0, stream>>>(
      attn_bf, wout_bf, b_out, out, nullptr, nullptr, nullptr, SEQ * BATCH, EMB, EMB);
}

// Round 17
// 145.049 us; speedup vs baseline: 1.8959x; 1.8959x over previous
//
#include <hip/hip_runtime.h>

// Problem constants (S, B, E, H) = (2048, 2, 1024, 16), D = 64
#define SEQ   2048
#define BATCH 2
#define NH    16
#define HD    64
#define EMB   1024

// Q is pre-scaled by log2(e)/8 at the QKV-projection epilogue, so both
// attention kernels compute exp(score/8) as exp2(S) with no per-element mul.
#define QSCALE 0.18033688011112042f

using bf16x8 = __attribute__((ext_vector_type(8))) short;  // 8 bf16 (4 VGPRs)
using f32x4  = __attribute__((ext_vector_type(4))) float;
using f32x16 = __attribute__((ext_vector_type(16))) float;

__device__ __forceinline__ unsigned short f2bf(float f) {
  unsigned int u = __float_as_uint(f);
  u += 0x7FFFu + ((u >> 16) & 1u);          // RNE
  return (unsigned short)(u >> 16);
}
__device__ __forceinline__ unsigned pk_bf16(float lo, float hi) {
  unsigned r;
  asm("v_cvt_pk_bf16_f32 %0, %1, %2" : "=v"(r) : "v"(lo), "v"(hi));
  return r;
}
// async global->LDS, 16B per lane; LDS dest = uniform base + lane*16
__device__ __forceinline__ void gload16(const void* g, void* l) {
  __builtin_amdgcn_global_load_lds(
      (const __attribute__((address_space(1))) unsigned int*)g,
      (__attribute__((address_space(3))) unsigned int*)l, 16, 0, 0);
}

// ---------------------------------------------------------------- cvt f32->bf16 (fused x, w_qkv, w_out)
__global__ __launch_bounds__(256) void cvt3_f32_bf16(
    const float* __restrict__ a, int na4,
    const float* __restrict__ b, int nb4,
    const float* __restrict__ c, int nc4,
    unsigned short* __restrict__ oa,
    unsigned short* __restrict__ ob,
    unsigned short* __restrict__ oc) {
  int i = blockIdx.x * 256 + threadIdx.x;
  const float* src;
  unsigned short* dst;
  int j = i;
  if (j < na4) { src = a; dst = oa; }
  else if ((j -= na4) < nb4) { src = b; dst = ob; }
  else { j -= nb4; if (j >= nc4) return; src = c; dst = oc; }
  float4 v = reinterpret_cast<const float4*>(src)[j];
  ushort4 o;
  o.x = f2bf(v.x); o.y = f2bf(v.y); o.z = f2bf(v.z); o.w = f2bf(v.w);
  reinterpret_cast<ushort4*>(dst)[j] = o;
}

// ---------------------------------------------------------------- GEMM C = A * B^T (+bias)
// A[M][K] bf16, B[N][K] bf16, fp32 accumulate. 128x128 tile, BK=64, 4 waves (2x2).
// Staging via global_load_lds dwordx4: linear LDS dest, pre-swizzled global src
// (slot [r][cc] holds global chunk cc^(r&7); readers use [r][j^(r&7)]).
// EPI==0: C fp32 row-major [M][N]
// EPI==1: scatter QKV -> Q (x QSCALE) / K bf16 [B][H][S][D], V -> V^T bf16 [B][H][D][S]
template <int EPI>
__global__ __launch_bounds__(256) void gemm_bt(
    const unsigned short* __restrict__ A,
    const unsigned short* __restrict__ B,
    const float* __restrict__ bias,
    float* __restrict__ Cf,
    unsigned short* __restrict__ Qb,
    unsigned short* __restrict__ Kb,
    unsigned short* __restrict__ VTb,
    int M, int N, int K) {
  __shared__ int4 As[128][8];
  __shared__ int4 Bs[128][8];
  const int tid = threadIdx.x;
  const int wid = tid >> 6, lane = tid & 63;
  const int wm = wid >> 1, wn = wid & 1;
  const int lg = lane >> 4, lr = lane & 15;
  const int lr8 = lane >> 3;
  const int lc8 = (lane & 7) ^ lr8;
  const int row0 = blockIdx.x * 128, col0 = blockIdx.y * 128;
  f32x4 acc[4][4] = {};
  for (int k0 = 0; k0 < K; k0 += 64) {
#pragma unroll
    for (int i = 0; i < 4; i++) {
      const int rb = wid * 32 + i * 8;
      gload16(&A[(size_t)(row0 + rb + lr8) * K + k0 + lc8 * 8], &As[rb][0]);
      gload16(&B[(size_t)(col0 + rb + lr8) * K + k0 + lc8 * 8], &Bs[rb][0]);
    }
    __syncthreads();
#pragma unroll
    for (int ks = 0; ks < 2; ks++) {
      bf16x8 af[4], bfr[4];
#pragma unroll
      for (int mi = 0; mi < 4; mi++) {
        int r = wm * 64 + mi * 16 + lr;
        af[mi] = *reinterpret_cast<const bf16x8*>(&As[r][(ks * 4 + lg) ^ (r & 7)]);
      }
#pragma unroll
      for (int ni = 0; ni < 4; ni++) {
        int r = wn * 64 + ni * 16 + lr;
        bfr[ni] = *reinterpret_cast<const bf16x8*>(&Bs[r][(ks * 4 + lg) ^ (r & 7)]);
      }
#pragma unroll
      for (int mi = 0; mi < 4; mi++)
#pragma unroll
        for (int ni = 0; ni < 4; ni++)
          acc[mi][ni] = __builtin_amdgcn_mfma_f32_16x16x32_bf16(af[mi], bfr[ni], acc[mi][ni], 0, 0, 0);
    }
    __syncthreads();
  }
  // epilogue: C/D layout col=lane&15, row=(lane>>4)*4+r  [m89-verified]
#pragma unroll
  for (int mi = 0; mi < 4; mi++)
#pragma unroll
    for (int ni = 0; ni < 4; ni++) {
      const int row_b = row0 + wm * 64 + mi * 16 + lg * 4;   // even
      const int col = col0 + wn * 64 + ni * 16 + lr;
      const float bs = bias[col];
      float v0 = acc[mi][ni][0] + bs;
      float v1 = acc[mi][ni][1] + bs;
      float v2 = acc[mi][ni][2] + bs;
      float v3 = acc[mi][ni][3] + bs;
      if (EPI == 0) {
        Cf[(size_t)(row_b + 0) * N + col] = v0;
        Cf[(size_t)(row_b + 1) * N + col] = v1;
        Cf[(size_t)(row_b + 2) * N + col] = v2;
        Cf[(size_t)(row_b + 3) * N + col] = v3;
      } else {
        const int which = col >> 10, rr = col & 1023;
        const int hh = rr >> 6, d = rr & 63;
        if (which == 2) {
          // V^T [b][h][d][s]; rows row_b+r = s*2+b -> b=r&1, s=s0+(r>>1)
          const int s0 = row_b >> 1;
          ushort2 p0; p0.x = f2bf(v0); p0.y = f2bf(v2);   // b=0
          ushort2 p1; p1.x = f2bf(v1); p1.y = f2bf(v3);   // b=1
          *reinterpret_cast<ushort2*>(&VTb[((size_t)((0 * NH + hh) * HD + d)) * SEQ + s0]) = p0;
          *reinterpret_cast<ushort2*>(&VTb[((size_t)((1 * NH + hh) * HD + d)) * SEQ + s0]) = p1;
        } else {
          unsigned short* dst = which == 0 ? Qb : Kb;
          const float sc = (which == 0) ? QSCALE : 1.0f;
          float vv[4] = {v0 * sc, v1 * sc, v2 * sc, v3 * sc};
#pragma unroll
          for (int r = 0; r < 4; r++) {
            int s = (row_b + r) >> 1, bb = r & 1;
            dst[(size_t)((bb * NH + hh) * SEQ + s) * HD + d] = f2bf(vv[r]);
          }
        }
      }
    }
}

// ---------------------------------------------------------------- attention pass 1 (v8, frozen)
__global__ __launch_bounds__(256, 2) void attn1(
    const unsigned short* __restrict__ Qb,
    const unsigned short* __restrict__ Kb,
    const unsigned short* __restrict__ VTb,
    unsigned short* __restrict__ attn_bf,
    float* __restrict__ lbuf) {
  __shared__ int4 Kt[2][64][8];
  __shared__ int4 Vt[2][64][8];
  const int tid = threadIdx.x;
  const int wid = tid >> 6, lane = tid & 63;
  const int l31 = lane & 31, lhi = lane >> 5;
  const int lr8 = lane >> 3;
  const int L = blockIdx.x;
  const int v = (L & 7) * 64 + (L >> 3);
  const int bh = v >> 4, stile = v & 15;
  const int b = bh >> 4, h = bh & 15;
  const int s0 = stile * 128 + wid * 32;
  const unsigned short* Qg = Qb + (size_t)bh * SEQ * HD;
  const unsigned short* Kg = Kb + (size_t)bh * SEQ * HD;
  const unsigned short* VTg = VTb + (size_t)bh * HD * SEQ;

  bf16x8 qf[4];
#pragma unroll
  for (int ks = 0; ks < 4; ks++)
    qf[ks] = *reinterpret_cast<const bf16x8*>(Qg + (size_t)(s0 + l31) * HD + ks * 16 + lhi * 8);

  auto stage = [&](int tg, int buf) {
#pragma unroll
    for (int i = 0; i < 2; i++) {
      const int rb = wid * 16 + i * 8;
      const int lc = (lane & 7) ^ (((rb >> 2) + lhi) & 7);
      gload16(Kg + (size_t)(tg * 64 + rb + lr8) * HD + lc * 8, &Kt[buf][rb][0]);
      gload16(VTg + (size_t)(rb + lr8) * SEQ + tg * 64 + lc * 8, &Vt[buf][rb][0]);
    }
  };
  const int swv = l31 >> 2;

  const f32x16 fz = {};
  f32x16 o[2] = {};
  f32x16 osum = {};
  const short one_bf = (short)0x3F80;
  const bf16x8 vone = {one_bf, one_bf, one_bf, one_bf, one_bf, one_bf, one_bf, one_bf};
  bf16x8 paq[4];
  bf16x8 vfr[2][4];

  auto qk = [&](int cur, f32x16 st[2]) {
#pragma unroll
    for (int ti = 0; ti < 2; ti++) {
      const int row = ti * 32 + l31;
      bf16x8 kf = *reinterpret_cast<const bf16x8*>(&Kt[cur][row][lhi ^ swv]);
      st[ti] = __builtin_amdgcn_mfma_f32_32x32x16_bf16(kf, qf[0], fz, 0, 0, 0);
    }
#pragma unroll
    for (int ks = 1; ks < 4; ks++)
#pragma unroll
      for (int ti = 0; ti < 2; ti++) {
        const int row = ti * 32 + l31;
        bf16x8 kf = *reinterpret_cast<const bf16x8*>(&Kt[cur][row][(ks * 2 + lhi) ^ swv]);
        st[ti] = __builtin_amdgcn_mfma_f32_32x32x16_bf16(kf, qf[ks], st[ti], 0, 0, 0);
      }
  };
  auto softpack = [&](const f32x16 st[2]) {
    float p[32];
#pragma unroll
    for (int ti = 0; ti < 2; ti++)
#pragma unroll
      for (int r = 0; r < 16; r++)
        p[ti * 16 + r] = __builtin_amdgcn_exp2f(st[ti][r]);
#pragma unroll
    for (int c = 0; c < 4; c++) {
      const int ti = c >> 1, cc = c & 1;
      const int pb = ti * 16 + cc * 8;
      unsigned w0 = pk_bf16(p[pb + 0], p[pb + 1]);
      unsigned w1 = pk_bf16(p[pb + 2], p[pb + 3]);
      unsigned w2 = pk_bf16(p[pb + 4], p[pb + 5]);
      unsigned w3 = pk_bf16(p[pb + 6], p[pb + 7]);
      asm volatile("v_permlane32_swap_b32 %0, %1" : "+v"(w0), "+v"(w2));
      asm volatile("v_permlane32_swap_b32 %0, %1" : "+v"(w1), "+v"(w3));
      union { unsigned u[4]; bf16x8 v; } pa;
      pa.u[0] = w0; pa.u[1] = w1; pa.u[2] = w2; pa.u[3] = w3;
      paq[c] = pa.v;
    }
  };
  auto loadv = [&](int cur) {
#pragma unroll
    for (int dt = 0; dt < 2; dt++)
#pragma unroll
      for (int c = 0; c < 4; c++) {
        const int row = dt * 32 + l31;
        vfr[dt][c] = *reinterpret_cast<const bf16x8*>(&Vt[cur][row][(c * 2 + lhi) ^ swv]);
      }
  };

  stage(0, 0);
  __syncthreads();

  {
    stage(1, 1);
    f32x16 st[2];
    __builtin_amdgcn_s_setprio(1);
    qk(0, st);
    __builtin_amdgcn_s_setprio(0);
    softpack(st);
    loadv(0);
    __syncthreads();
  }

  for (int t = 1; t < 32; t++) {
    const int cur = t & 1;
    if (t + 1 < 32) stage(t + 1, cur ^ 1);
    f32x16 st[2];
    __builtin_amdgcn_s_setprio(1);
#pragma unroll
    for (int c = 0; c < 4; c++) {
#pragma unroll
      for (int dt = 0; dt < 2; dt++)
        o[dt] = __builtin_amdgcn_mfma_f32_32x32x16_bf16(paq[c], vfr[dt][c], o[dt], 0, 0, 0);
      osum = __builtin_amdgcn_mfma_f32_32x32x16_bf16(paq[c], vone, osum, 0, 0, 0);
    }
    qk(cur, st);
    __builtin_amdgcn_s_setprio(0);
    softpack(st);
    loadv(cur);
    __syncthreads();
  }
#pragma unroll
  for (int c = 0; c < 4; c++) {
#pragma unroll
    for (int dt = 0; dt < 2; dt++)
      o[dt] = __builtin_amdgcn_mfma_f32_32x32x16_bf16(paq[c], vfr[dt][c], o[dt], 0, 0, 0);
    osum = __builtin_amdgcn_mfma_f32_32x32x16_bf16(paq[c], vone, osum, 0, 0, 0);
  }

  if (l31 == 0) {
#pragma unroll
    for (int r = 0; r < 16; r++)
      lbuf[(size_t)bh * SEQ + s0 + (r & 3) + 8 * (r >> 2) + 4 * lhi] = osum[r];
  }

#pragma unroll
  for (int r = 0; r < 16; r++) {
    float inv = __builtin_amdgcn_rcpf(osum[r]);
    const int s = s0 + (r & 3) + 8 * (r >> 2) + 4 * lhi;
#pragma unroll
    for (int dt = 0; dt < 2; dt++) {
      float ov = o[dt][r] * inv;
      attn_bf[((size_t)s * BATCH + b) * EMB + h * HD + dt * 32 + l31] = f2bf(ov);
    }
  }
}

// ---------------------------------------------------------------- attention pass 2 (v8 — frozen known-good)
// 2 heads per barrier, Q pair staged in LDS, natural register allocation.
// (All attempts past this point spilled or serialized: forced 3 blocks/CU
// spilled (R14), Q-in-registers via lambda-ref arrays spilled (R16),
// heterogeneous fusion with gemm2 serialized (R13).)
__global__ __launch_bounds__(256, 2) void attn2(
    const unsigned short* __restrict__ Qb,
    const unsigned short* __restrict__ Kb,
    const float* __restrict__ lbuf,
    float* __restrict__ avg_out) {
  const int b = blockIdx.z;
  const int s0 = blockIdx.y * 64;
  const int tc0 = blockIdx.x * 256;
  __shared__ int4 Qs[2][64][8];      // 16 KB  [head-of-pair]
  __shared__ int4 Ks[2][2][64][8];   // 32 KB  [dbuf][head-of-pair]
  __shared__ float lls[NH][64];      // 1/(NH*l)
  const int tid = threadIdx.x;
  const int wid = tid >> 6, lane = tid & 63;
  const int wm = wid >> 1, wn = wid & 1;
  const int lg = lane >> 4, lr = lane & 15;
  const int lr8 = lane >> 3;
  const int lc8 = (lane & 7) ^ lr8;

  for (int i = tid; i < NH * 64; i += 256) {
    int hh = i >> 6, r = i & 63;
    lls[hh][r] = 1.0f / ((float)NH * lbuf[(b * NH + hh) * SEQ + s0 + r]);
  }

  const size_t bh0 = (size_t)(b * NH) * SEQ;

  auto stageK = [&](const unsigned short* src, int buf, int hsel) {
#pragma unroll
    for (int i = 0; i < 2; i++) {
      const int rb = wid * 16 + i * 8;
      gload16(src + (size_t)(rb + lr8) * HD + lc8 * 8, &Ks[buf][hsel][rb][0]);
    }
  };
  auto stageQ = [&](const unsigned short* src, int hsel) {
#pragma unroll
    for (int i = 0; i < 2; i++) {
      const int rb = wid * 16 + i * 8;
      gload16(src + (size_t)(rb + lr8) * HD + lc8 * 8, &Qs[hsel][rb][0]);
    }
  };

  stageQ(Qb + (bh0 + s0) * HD, 0);
  stageQ(Qb + (bh0 + SEQ + s0) * HD, 1);
  stageK(Kb + (bh0 + tc0) * HD, 0, 0);
  stageK(Kb + (bh0 + SEQ + tc0) * HD, 0, 1);
  __syncthreads();

  const f32x4 fz4 = {};
  f32x4 avg[4][2][2] = {};

  for (int hp = 0; hp < NH / 2; hp++) {
    const int h0 = 2 * hp, h1 = h0 + 1;
    bf16x8 af[2][2][2];   // [head][mi][ks]
#pragma unroll
    for (int hh = 0; hh < 2; hh++)
#pragma unroll
      for (int mi = 0; mi < 2; mi++) {
        int r = wm * 32 + mi * 16 + lr;
#pragma unroll
        for (int ks = 0; ks < 2; ks++)
          af[hh][mi][ks] = *reinterpret_cast<const bf16x8*>(&Qs[hh][r][(ks * 4 + lg) ^ (r & 7)]);
      }
    float linv[2][2][4];
#pragma unroll
    for (int hh = 0; hh < 2; hh++)
#pragma unroll
      for (int mi = 0; mi < 2; mi++)
#pragma unroll
        for (int r = 0; r < 4; r++)
          linv[hh][mi][r] = lls[h0 + hh][wm * 32 + mi * 16 + lg * 4 + r];

    const unsigned short* Kg0 = Kb + (bh0 + (size_t)h0 * SEQ + tc0) * HD;
    const unsigned short* Kg1 = Kb + (bh0 + (size_t)h1 * SEQ + tc0) * HD;

    for (int t0 = 0; t0 < 4; t0++) {
      const int cur = t0 & 1;
      if (t0 < 3) {
        stageK(Kg0 + (size_t)(t0 + 1) * 64 * HD, cur ^ 1, 0);
        stageK(Kg1 + (size_t)(t0 + 1) * 64 * HD, cur ^ 1, 1);
      } else if (hp + 1 < NH / 2) {
        stageK(Kb + (bh0 + (size_t)(h0 + 2) * SEQ + tc0) * HD, cur ^ 1, 0);
        stageK(Kb + (bh0 + (size_t)(h1 + 2) * SEQ + tc0) * HD, cur ^ 1, 1);
        stageQ(Qb + (bh0 + (size_t)(h0 + 2) * SEQ + s0) * HD, 0);
        stageQ(Qb + (bh0 + (size_t)(h1 + 2) * SEQ + s0) * HD, 1);
      }
      f32x4 sacc[2][2][2];   // [head][mi][ni]
      __builtin_amdgcn_s_setprio(1);
#pragma unroll
      for (int hh = 0; hh < 2; hh++)
#pragma unroll
        for (int ks = 0; ks < 2; ks++) {
          bf16x8 bk[2];
#pragma unroll
          for (int ni = 0; ni < 2; ni++) {
            int rk = wn * 32 + ni * 16 + lr;
            bk[ni] = *reinterpret_cast<const bf16x8*>(&Ks[cur][hh][rk][(ks * 4 + lg) ^ (rk & 7)]);
          }
#pragma unroll
          for (int mi = 0; mi < 2; mi++)
#pragma unroll
            for (int ni = 0; ni < 2; ni++)
              sacc[hh][mi][ni] = __builtin_amdgcn_mfma_f32_16x16x32_bf16(
                  af[hh][mi][ks], bk[ni], ks == 0 ? fz4 : sacc[hh][mi][ni], 0, 0, 0);
        }
      __builtin_amdgcn_s_setprio(0);
#pragma unroll
      for (int hh = 0; hh < 2; hh++)
#pragma unroll
        for (int mi = 0; mi < 2; mi++)
#pragma unroll
          for (int ni = 0; ni < 2; ni++)
#pragma unroll
            for (int r = 0; r < 4; r++)
              avg[t0][mi][ni][r] += __builtin_amdgcn_exp2f(sacc[hh][mi][ni][r]) * linv[hh][mi][r];
      __syncthreads();
    }
  }

#pragma unroll
  for (int t0 = 0; t0 < 4; t0++)
#pragma unroll
    for (int mi = 0; mi < 2; mi++)
#pragma unroll
      for (int ni = 0; ni < 2; ni++)
#pragma unroll
        for (int r = 0; r < 4; r++) {
          int s = s0 + wm * 32 + mi * 16 + lg * 4 + r;
          int t = tc0 + t0 * 64 + wn * 32 + ni * 16 + lr;
          avg_out[((size_t)b * SEQ + s) * SEQ + t] = avg[t0][mi][ni][r];
        }
}

// ---------------------------------------------------------------- launch
extern "C" void kernel_launch(void* const* d_in, const int* in_sizes, int n_in,
                              void* d_out, int out_size, void* d_ws, size_t ws_size,
                              hipStream_t stream) {
  const float* x     = (const float*)d_in[0];   // [S,B,E]
  const float* w_qkv = (const float*)d_in[1];   // [3E,E]
  const float* b_qkv = (const float*)d_in[2];   // [3E]
  const float* w_out = (const float*)d_in[3];   // [E,E]
  const float* b_out = (const float*)d_in[4];   // [E]
  float* out = (float*)d_out;                         // [S,B,E] fp32
  float* avg = out + (size_t)SEQ * BATCH * EMB;       // [B,S,S] fp32

  char* ws = (char*)d_ws;
  size_t off = 0;
  unsigned short* x_bf    = (unsigned short*)(ws + off); off += (size_t)SEQ * BATCH * EMB * 2;       // 8 MB
  unsigned short* wqkv_bf = (unsigned short*)(ws + off); off += (size_t)3 * EMB * EMB * 2;           // 6 MB
  unsigned short* wout_bf = (unsigned short*)(ws + off); off += (size_t)EMB * EMB * 2;               // 2 MB
  unsigned short* Qbuf    = (unsigned short*)(ws + off); off += (size_t)BATCH * NH * SEQ * HD * 2;   // 8 MB
  unsigned short* Kbuf    = (unsigned short*)(ws + off); off += (size_t)BATCH * NH * SEQ * HD * 2;   // 8 MB
  unsigned short* VTbuf   = (unsigned short*)(ws + off); off += (size_t)BATCH * NH * HD * SEQ * 2;   // 8 MB
  unsigned short* attn_bf = (unsigned short*)(ws + off); off += (size_t)SEQ * BATCH * EMB * 2;       // 8 MB
  float*          lbuf    = (float*)(ws + off);          off += (size_t)BATCH * NH * SEQ * 4;        // 256 KB

  // 1) convert inputs to bf16 (single fused kernel)
  {
    const int na4 = SEQ * BATCH * EMB / 4;
    const int nb4 = 3 * EMB * EMB / 4;
    const int nc4 = EMB * EMB / 4;
    const int nblk = (na4 + nb4 + nc4 + 255) / 256;
    cvt3_f32_bf16<<<nblk, 256, 0, stream>>>(x, na4, w_qkv, nb4, w_out, nc4,
                                            x_bf, wqkv_bf, wout_bf);
  }

  // 2) QKV projection, scatter to Q (pre-scaled) / K [B][H][S][D] + V^T [B][H][D][S]
  gemm_bt<1><<<dim3(SEQ * BATCH / 128, 3 * EMB / 128), 256, 0, stream>>>(
      x_bf, wqkv_bf, b_qkv, nullptr, Qbuf, Kbuf, VTbuf, SEQ * BATCH, 3 * EMB, EMB);

  // 3) attention core (v8, frozen)
  attn1<<<512, 256, 0, stream>>>(Qbuf, Kbuf, VTbuf, attn_bf, lbuf);

  // 4) attention average over heads (v8, frozen known-good)
  attn2<<<dim3(SEQ / 256, SEQ / 64, BATCH), 256, 0, stream>>>(Qbuf, Kbuf, lbuf, avg);

  // 5) output projection -> d_out
  gemm_bt<0><<<dim3(SEQ * BATCH / 128, EMB / 128), 256, 0, stream>>>(
      attn_bf, wout_bf, b_out, out, nullptr, nullptr, nullptr, SEQ * BATCH, EMB, EMB);
}

// Round 18
// 144.491 us; speedup vs baseline: 1.9032x; 1.0039x over previous
//
#include <hip/hip_runtime.h>

// Problem constants (S, B, E, H) = (2048, 2, 1024, 16), D = 64
#define SEQ   2048
#define BATCH 2
#define NH    16
#define HD    64
#define EMB   1024

// Q is pre-scaled by log2(e)/8 at the QKV-projection epilogue, so both
// attention kernels compute exp(score/8) as exp2(S) with no per-element mul.
#define QSCALE 0.18033688011112042f

using bf16x8 = __attribute__((ext_vector_type(8))) short;  // 8 bf16 (4 VGPRs)
using f32x4  = __attribute__((ext_vector_type(4))) float;
using f32x16 = __attribute__((ext_vector_type(16))) float;

__device__ __forceinline__ unsigned short f2bf(float f) {
  unsigned int u = __float_as_uint(f);
  u += 0x7FFFu + ((u >> 16) & 1u);          // RNE
  return (unsigned short)(u >> 16);
}
__device__ __forceinline__ unsigned pk_bf16(float lo, float hi) {
  unsigned r;
  asm("v_cvt_pk_bf16_f32 %0, %1, %2" : "=v"(r) : "v"(lo), "v"(hi));
  return r;
}
// async global->LDS, 16B per lane; LDS dest = uniform base + lane*16
__device__ __forceinline__ void gload16(const void* g, void* l) {
  __builtin_amdgcn_global_load_lds(
      (const __attribute__((address_space(1))) unsigned int*)g,
      (__attribute__((address_space(3))) unsigned int*)l, 16, 0, 0);
}

// ---------------------------------------------------------------- cvt f32->bf16 (fused x, w_qkv, w_out)
__global__ __launch_bounds__(256) void cvt3_f32_bf16(
    const float* __restrict__ a, int na4,
    const float* __restrict__ b, int nb4,
    const float* __restrict__ c, int nc4,
    unsigned short* __restrict__ oa,
    unsigned short* __restrict__ ob,
    unsigned short* __restrict__ oc) {
  int i = blockIdx.x * 256 + threadIdx.x;
  const float* src;
  unsigned short* dst;
  int j = i;
  if (j < na4) { src = a; dst = oa; }
  else if ((j -= na4) < nb4) { src = b; dst = ob; }
  else { j -= nb4; if (j >= nc4) return; src = c; dst = oc; }
  float4 v = reinterpret_cast<const float4*>(src)[j];
  ushort4 o;
  o.x = f2bf(v.x); o.y = f2bf(v.y); o.z = f2bf(v.z); o.w = f2bf(v.w);
  reinterpret_cast<ushort4*>(dst)[j] = o;
}

// ---------------------------------------------------------------- GEMM C = A * B^T (+bias)
// A[M][K] bf16, B[N][K] bf16, fp32 accumulate. 128x128 tile, BK=64, 4 waves (2x2).
// Staging via global_load_lds dwordx4: linear LDS dest, pre-swizzled global src
// (slot [r][cc] holds global chunk cc^(r&7); readers use [r][j^(r&7)]).
// EPI==0: C fp32 row-major [M][N]
// EPI==1: scatter QKV -> Q (x QSCALE) / K bf16 [B][H][S][D], V -> V^T bf16 [B][H][D][S]
template <int EPI>
__global__ __launch_bounds__(256) void gemm_bt(
    const unsigned short* __restrict__ A,
    const unsigned short* __restrict__ B,
    const float* __restrict__ bias,
    float* __restrict__ Cf,
    unsigned short* __restrict__ Qb,
    unsigned short* __restrict__ Kb,
    unsigned short* __restrict__ VTb,
    int M, int N, int K) {
  __shared__ int4 As[128][8];
  __shared__ int4 Bs[128][8];
  const int tid = threadIdx.x;
  const int wid = tid >> 6, lane = tid & 63;
  const int wm = wid >> 1, wn = wid & 1;
  const int lg = lane >> 4, lr = lane & 15;
  const int lr8 = lane >> 3;
  const int lc8 = (lane & 7) ^ lr8;
  const int row0 = blockIdx.x * 128, col0 = blockIdx.y * 128;
  f32x4 acc[4][4] = {};
  for (int k0 = 0; k0 < K; k0 += 64) {
#pragma unroll
    for (int i = 0; i < 4; i++) {
      const int rb = wid * 32 + i * 8;
      gload16(&A[(size_t)(row0 + rb + lr8) * K + k0 + lc8 * 8], &As[rb][0]);
      gload16(&B[(size_t)(col0 + rb + lr8) * K + k0 + lc8 * 8], &Bs[rb][0]);
    }
    __syncthreads();
#pragma unroll
    for (int ks = 0; ks < 2; ks++) {
      bf16x8 af[4], bfr[4];
#pragma unroll
      for (int mi = 0; mi < 4; mi++) {
        int r = wm * 64 + mi * 16 + lr;
        af[mi] = *reinterpret_cast<const bf16x8*>(&As[r][(ks * 4 + lg) ^ (r & 7)]);
      }
#pragma unroll
      for (int ni = 0; ni < 4; ni++) {
        int r = wn * 64 + ni * 16 + lr;
        bfr[ni] = *reinterpret_cast<const bf16x8*>(&Bs[r][(ks * 4 + lg) ^ (r & 7)]);
      }
#pragma unroll
      for (int mi = 0; mi < 4; mi++)
#pragma unroll
        for (int ni = 0; ni < 4; ni++)
          acc[mi][ni] = __builtin_amdgcn_mfma_f32_16x16x32_bf16(af[mi], bfr[ni], acc[mi][ni], 0, 0, 0);
    }
    __syncthreads();
  }
  // epilogue: C/D layout col=lane&15, row=(lane>>4)*4+r  [m89-verified]
#pragma unroll
  for (int mi = 0; mi < 4; mi++)
#pragma unroll
    for (int ni = 0; ni < 4; ni++) {
      const int row_b = row0 + wm * 64 + mi * 16 + lg * 4;   // even
      const int col = col0 + wn * 64 + ni * 16 + lr;
      const float bs = bias[col];
      float v0 = acc[mi][ni][0] + bs;
      float v1 = acc[mi][ni][1] + bs;
      float v2 = acc[mi][ni][2] + bs;
      float v3 = acc[mi][ni][3] + bs;
      if (EPI == 0) {
        Cf[(size_t)(row_b + 0) * N + col] = v0;
        Cf[(size_t)(row_b + 1) * N + col] = v1;
        Cf[(size_t)(row_b + 2) * N + col] = v2;
        Cf[(size_t)(row_b + 3) * N + col] = v3;
      } else {
        const int which = col >> 10, rr = col & 1023;
        const int hh = rr >> 6, d = rr & 63;
        if (which == 2) {
          // V^T [b][h][d][s]; rows row_b+r = s*2+b -> b=r&1, s=s0+(r>>1)
          const int s0 = row_b >> 1;
          ushort2 p0; p0.x = f2bf(v0); p0.y = f2bf(v2);   // b=0
          ushort2 p1; p1.x = f2bf(v1); p1.y = f2bf(v3);   // b=1
          *reinterpret_cast<ushort2*>(&VTb[((size_t)((0 * NH + hh) * HD + d)) * SEQ + s0]) = p0;
          *reinterpret_cast<ushort2*>(&VTb[((size_t)((1 * NH + hh) * HD + d)) * SEQ + s0]) = p1;
        } else {
          unsigned short* dst = which == 0 ? Qb : Kb;
          const float sc = (which == 0) ? QSCALE : 1.0f;
          float vv[4] = {v0 * sc, v1 * sc, v2 * sc, v3 * sc};
#pragma unroll
          for (int r = 0; r < 4; r++) {
            int s = (row_b + r) >> 1, bb = r & 1;
            dst[(size_t)((bb * NH + hh) * SEQ + s) * HD + d] = f2bf(vv[r]);
          }
        }
      }
    }
}

// ---------------------------------------------------------------- attention pass 1 (v9)
// v8 pipeline with KVBLK=128: 2 t-tiles per barrier window (barriers 33 -> 17).
// LDS 64 KB (2 dbuf x 2 sub x (K 8KB + V 8KB)), still 2 blocks/CU.
// Per sub-tile the math/indexing is byte-identical to v8.
__global__ __launch_bounds__(256, 2) void attn1(
    const unsigned short* __restrict__ Qb,
    const unsigned short* __restrict__ Kb,
    const unsigned short* __restrict__ VTb,
    unsigned short* __restrict__ attn_bf,
    float* __restrict__ lbuf) {
  __shared__ int4 Kt[2][2][64][8];   // [dbuf][sub][t-row][chunk]
  __shared__ int4 Vt[2][2][64][8];   // [dbuf][sub][d-row][t chunks]
  const int tid = threadIdx.x;
  const int wid = tid >> 6, lane = tid & 63;
  const int l31 = lane & 31, lhi = lane >> 5;
  const int lr8 = lane >> 3;
  const int L = blockIdx.x;
  const int v = (L & 7) * 64 + (L >> 3);
  const int bh = v >> 4, stile = v & 15;
  const int b = bh >> 4, h = bh & 15;
  const int s0 = stile * 128 + wid * 32;
  const unsigned short* Qg = Qb + (size_t)bh * SEQ * HD;
  const unsigned short* Kg = Kb + (size_t)bh * SEQ * HD;
  const unsigned short* VTg = VTb + (size_t)bh * HD * SEQ;

  bf16x8 qf[4];
#pragma unroll
  for (int ks = 0; ks < 4; ks++)
    qf[ks] = *reinterpret_cast<const bf16x8*>(Qg + (size_t)(s0 + l31) * HD + ks * 16 + lhi * 8);

  // stage one PAIR of tiles (2*pg, 2*pg+1) into buffer buf
  auto stage = [&](int pg, int buf) {
#pragma unroll
    for (int sub = 0; sub < 2; sub++) {
      const int tg = pg * 2 + sub;
#pragma unroll
      for (int i = 0; i < 2; i++) {
        const int rb = wid * 16 + i * 8;
        const int lc = (lane & 7) ^ (((rb >> 2) + lhi) & 7);
        gload16(Kg + (size_t)(tg * 64 + rb + lr8) * HD + lc * 8, &Kt[buf][sub][rb][0]);
        gload16(VTg + (size_t)(rb + lr8) * SEQ + tg * 64 + lc * 8, &Vt[buf][sub][rb][0]);
      }
    }
  };
  const int swv = l31 >> 2;

  const f32x16 fz = {};
  f32x16 o[2] = {};
  f32x16 osum = {};
  const short one_bf = (short)0x3F80;
  const bf16x8 vone = {one_bf, one_bf, one_bf, one_bf, one_bf, one_bf, one_bf, one_bf};
  bf16x8 paq[4];
  bf16x8 vfr[2][4];

  auto qk = [&](int cur, int sub, f32x16 st[2]) {
#pragma unroll
    for (int ti = 0; ti < 2; ti++) {
      const int row = ti * 32 + l31;
      bf16x8 kf = *reinterpret_cast<const bf16x8*>(&Kt[cur][sub][row][lhi ^ swv]);
      st[ti] = __builtin_amdgcn_mfma_f32_32x32x16_bf16(kf, qf[0], fz, 0, 0, 0);
    }
#pragma unroll
    for (int ks = 1; ks < 4; ks++)
#pragma unroll
      for (int ti = 0; ti < 2; ti++) {
        const int row = ti * 32 + l31;
        bf16x8 kf = *reinterpret_cast<const bf16x8*>(&Kt[cur][sub][row][(ks * 2 + lhi) ^ swv]);
        st[ti] = __builtin_amdgcn_mfma_f32_32x32x16_bf16(kf, qf[ks], st[ti], 0, 0, 0);
      }
  };
  auto pvburst = [&]() {
#pragma unroll
    for (int c = 0; c < 4; c++) {
#pragma unroll
      for (int dt = 0; dt < 2; dt++)
        o[dt] = __builtin_amdgcn_mfma_f32_32x32x16_bf16(paq[c], vfr[dt][c], o[dt], 0, 0, 0);
      osum = __builtin_amdgcn_mfma_f32_32x32x16_bf16(paq[c], vone, osum, 0, 0, 0);
    }
  };
  auto softpack = [&](const f32x16 st[2]) {
    float p[32];
#pragma unroll
    for (int ti = 0; ti < 2; ti++)
#pragma unroll
      for (int r = 0; r < 16; r++)
        p[ti * 16 + r] = __builtin_amdgcn_exp2f(st[ti][r]);
#pragma unroll
    for (int c = 0; c < 4; c++) {
      const int ti = c >> 1, cc = c & 1;
      const int pb = ti * 16 + cc * 8;
      unsigned w0 = pk_bf16(p[pb + 0], p[pb + 1]);
      unsigned w1 = pk_bf16(p[pb + 2], p[pb + 3]);
      unsigned w2 = pk_bf16(p[pb + 4], p[pb + 5]);
      unsigned w3 = pk_bf16(p[pb + 6], p[pb + 7]);
      asm volatile("v_permlane32_swap_b32 %0, %1" : "+v"(w0), "+v"(w2));
      asm volatile("v_permlane32_swap_b32 %0, %1" : "+v"(w1), "+v"(w3));
      union { unsigned u[4]; bf16x8 v; } pa;
      pa.u[0] = w0; pa.u[1] = w1; pa.u[2] = w2; pa.u[3] = w3;
      paq[c] = pa.v;
    }
  };
  auto loadv = [&](int cur, int sub) {
#pragma unroll
    for (int dt = 0; dt < 2; dt++)
#pragma unroll
      for (int c = 0; c < 4; c++) {
        const int row = dt * 32 + l31;
        vfr[dt][c] = *reinterpret_cast<const bf16x8*>(&Vt[cur][sub][row][(c * 2 + lhi) ^ swv]);
      }
  };

  stage(0, 0);
  __syncthreads();

  // ---- pair 0: sub0 has no PV yet
  {
    stage(1, 1);
    f32x16 st[2];
    __builtin_amdgcn_s_setprio(1);
    qk(0, 0, st);
    __builtin_amdgcn_s_setprio(0);
    softpack(st);
    loadv(0, 0);
    f32x16 st2[2];
    __builtin_amdgcn_s_setprio(1);
    pvburst();            // PV(tile 0)
    qk(0, 1, st2);        // QK(tile 1)
    __builtin_amdgcn_s_setprio(0);
    softpack(st2);
    loadv(0, 1);
    __syncthreads();
  }

  for (int p = 1; p < 16; p++) {
    const int cur = p & 1;
    if (p + 1 < 16) stage(p + 1, cur ^ 1);
#pragma unroll
    for (int sub = 0; sub < 2; sub++) {
      f32x16 st[2];
      __builtin_amdgcn_s_setprio(1);
      pvburst();          // PV(previous tile) [reg-only]
      qk(cur, sub, st);
      __builtin_amdgcn_s_setprio(0);
      softpack(st);
      loadv(cur, sub);
    }
    __syncthreads();
  }
  // ---- epilogue: PV(tile 31)
  pvburst();

  // lbuf: osum[r] holds Sum_t P for row s0 + (r&3)+8*(r>>2)+4*lhi (all l31 copies)
  if (l31 == 0) {
#pragma unroll
    for (int r = 0; r < 16; r++)
      lbuf[(size_t)bh * SEQ + s0 + (r & 3) + 8 * (r >> 2) + 4 * lhi] = osum[r];
  }

  // epilogue: O row s = s0 + (r&3)+8*(r>>2)+4*lhi, col d = dt*32+l31
#pragma unroll
  for (int r = 0; r < 16; r++) {
    float inv = __builtin_amdgcn_rcpf(osum[r]);
    const int s = s0 + (r & 3) + 8 * (r >> 2) + 4 * lhi;
#pragma unroll
    for (int dt = 0; dt < 2; dt++) {
      float ov = o[dt][r] * inv;
      attn_bf[((size_t)s * BATCH + b) * EMB + h * HD + dt * 32 + l31] = f2bf(ov);
    }
  }
}

// ---------------------------------------------------------------- attention pass 2 (v8 — frozen known-good)
// 2 heads per barrier, Q pair staged in LDS, natural register allocation.
__global__ __launch_bounds__(256, 2) void attn2(
    const unsigned short* __restrict__ Qb,
    const unsigned short* __restrict__ Kb,
    const float* __restrict__ lbuf,
    float* __restrict__ avg_out) {
  const int b = blockIdx.z;
  const int s0 = blockIdx.y * 64;
  const int tc0 = blockIdx.x * 256;
  __shared__ int4 Qs[2][64][8];      // 16 KB  [head-of-pair]
  __shared__ int4 Ks[2][2][64][8];   // 32 KB  [dbuf][head-of-pair]
  __shared__ float lls[NH][64];      // 1/(NH*l)
  const int tid = threadIdx.x;
  const int wid = tid >> 6, lane = tid & 63;
  const int wm = wid >> 1, wn = wid & 1;
  const int lg = lane >> 4, lr = lane & 15;
  const int lr8 = lane >> 3;
  const int lc8 = (lane & 7) ^ lr8;

  for (int i = tid; i < NH * 64; i += 256) {
    int hh = i >> 6, r = i & 63;
    lls[hh][r] = 1.0f / ((float)NH * lbuf[(b * NH + hh) * SEQ + s0 + r]);
  }

  const size_t bh0 = (size_t)(b * NH) * SEQ;

  auto stageK = [&](const unsigned short* src, int buf, int hsel) {
#pragma unroll
    for (int i = 0; i < 2; i++) {
      const int rb = wid * 16 + i * 8;
      gload16(src + (size_t)(rb + lr8) * HD + lc8 * 8, &Ks[buf][hsel][rb][0]);
    }
  };
  auto stageQ = [&](const unsigned short* src, int hsel) {
#pragma unroll
    for (int i = 0; i < 2; i++) {
      const int rb = wid * 16 + i * 8;
      gload16(src + (size_t)(rb + lr8) * HD + lc8 * 8, &Qs[hsel][rb][0]);
    }
  };

  stageQ(Qb + (bh0 + s0) * HD, 0);
  stageQ(Qb + (bh0 + SEQ + s0) * HD, 1);
  stageK(Kb + (bh0 + tc0) * HD, 0, 0);
  stageK(Kb + (bh0 + SEQ + tc0) * HD, 0, 1);
  __syncthreads();

  const f32x4 fz4 = {};
  f32x4 avg[4][2][2] = {};

  for (int hp = 0; hp < NH / 2; hp++) {
    const int h0 = 2 * hp, h1 = h0 + 1;
    bf16x8 af[2][2][2];   // [head][mi][ks]
#pragma unroll
    for (int hh = 0; hh < 2; hh++)
#pragma unroll
      for (int mi = 0; mi < 2; mi++) {
        int r = wm * 32 + mi * 16 + lr;
#pragma unroll
        for (int ks = 0; ks < 2; ks++)
          af[hh][mi][ks] = *reinterpret_cast<const bf16x8*>(&Qs[hh][r][(ks * 4 + lg) ^ (r & 7)]);
      }
    float linv[2][2][4];
#pragma unroll
    for (int hh = 0; hh < 2; hh++)
#pragma unroll
      for (int mi = 0; mi < 2; mi++)
#pragma unroll
        for (int r = 0; r < 4; r++)
          linv[hh][mi][r] = lls[h0 + hh][wm * 32 + mi * 16 + lg * 4 + r];

    const unsigned short* Kg0 = Kb + (bh0 + (size_t)h0 * SEQ + tc0) * HD;
    const unsigned short* Kg1 = Kb + (bh0 + (size_t)h1 * SEQ + tc0) * HD;

    for (int t0 = 0; t0 < 4; t0++) {
      const int cur = t0 & 1;
      if (t0 < 3) {
        stageK(Kg0 + (size_t)(t0 + 1) * 64 * HD, cur ^ 1, 0);
        stageK(Kg1 + (size_t)(t0 + 1) * 64 * HD, cur ^ 1, 1);
      } else if (hp + 1 < NH / 2) {
        stageK(Kb + (bh0 + (size_t)(h0 + 2) * SEQ + tc0) * HD, cur ^ 1, 0);
        stageK(Kb + (bh0 + (size_t)(h1 + 2) * SEQ + tc0) * HD, cur ^ 1, 1);
        stageQ(Qb + (bh0 + (size_t)(h0 + 2) * SEQ + s0) * HD, 0);
        stageQ(Qb + (bh0 + (size_t)(h1 + 2) * SEQ + s0) * HD, 1);
      }
      f32x4 sacc[2][2][2];   // [head][mi][ni]
      __builtin_amdgcn_s_setprio(1);
#pragma unroll
      for (int hh = 0; hh < 2; hh++)
#pragma unroll
        for (int ks = 0; ks < 2; ks++) {
          bf16x8 bk[2];
#pragma unroll
          for (int ni = 0; ni < 2; ni++) {
            int rk = wn * 32 + ni * 16 + lr;
            bk[ni] = *reinterpret_cast<const bf16x8*>(&Ks[cur][hh][rk][(ks * 4 + lg) ^ (rk & 7)]);
          }
#pragma unroll
          for (int mi = 0; mi < 2; mi++)
#pragma unroll
            for (int ni = 0; ni < 2; ni++)
              sacc[hh][mi][ni] = __builtin_amdgcn_mfma_f32_16x16x32_bf16(
                  af[hh][mi][ks], bk[ni], ks == 0 ? fz4 : sacc[hh][mi][ni], 0, 0, 0);
        }
      __builtin_amdgcn_s_setprio(0);
#pragma unroll
      for (int hh = 0; hh < 2; hh++)
#pragma unroll
        for (int mi = 0; mi < 2; mi++)
#pragma unroll
          for (int ni = 0; ni < 2; ni++)
#pragma unroll
            for (int r = 0; r < 4; r++)
              avg[t0][mi][ni][r] += __builtin_amdgcn_exp2f(sacc[hh][mi][ni][r]) * linv[hh][mi][r];
      __syncthreads();
    }
  }

#pragma unroll
  for (int t0 = 0; t0 < 4; t0++)
#pragma unroll
    for (int mi = 0; mi < 2; mi++)
#pragma unroll
      for (int ni = 0; ni < 2; ni++)
#pragma unroll
        for (int r = 0; r < 4; r++) {
          int s = s0 + wm * 32 + mi * 16 + lg * 4 + r;
          int t = tc0 + t0 * 64 + wn * 32 + ni * 16 + lr;
          avg_out[((size_t)b * SEQ + s) * SEQ + t] = avg[t0][mi][ni][r];
        }
}

// ---------------------------------------------------------------- launch
extern "C" void kernel_launch(void* const* d_in, const int* in_sizes, int n_in,
                              void* d_out, int out_size, void* d_ws, size_t ws_size,
                              hipStream_t stream) {
  const float* x     = (const float*)d_in[0];   // [S,B,E]
  const float* w_qkv = (const float*)d_in[1];   // [3E,E]
  const float* b_qkv = (const float*)d_in[2];   // [3E]
  const float* w_out = (const float*)d_in[3];   // [E,E]
  const float* b_out = (const float*)d_in[4];   // [E]
  float* out = (float*)d_out;                         // [S,B,E] fp32
  float* avg = out + (size_t)SEQ * BATCH * EMB;       // [B,S,S] fp32

  char* ws = (char*)d_ws;
  size_t off = 0;
  unsigned short* x_bf    = (unsigned short*)(ws + off); off += (size_t)SEQ * BATCH * EMB * 2;       // 8 MB
  unsigned short* wqkv_bf = (unsigned short*)(ws + off); off += (size_t)3 * EMB * EMB * 2;           // 6 MB
  unsigned short* wout_bf = (unsigned short*)(ws + off); off += (size_t)EMB * EMB * 2;               // 2 MB
  unsigned short* Qbuf    = (unsigned short*)(ws + off); off += (size_t)BATCH * NH * SEQ * HD * 2;   // 8 MB
  unsigned short* Kbuf    = (unsigned short*)(ws + off); off += (size_t)BATCH * NH * SEQ * HD * 2;   // 8 MB
  unsigned short* VTbuf   = (unsigned short*)(ws + off); off += (size_t)BATCH * NH * HD * SEQ * 2;   // 8 MB
  unsigned short* attn_bf = (unsigned short*)(ws + off); off += (size_t)SEQ * BATCH * EMB * 2;       // 8 MB
  float*          lbuf    = (float*)(ws + off);          off += (size_t)BATCH * NH * SEQ * 4;        // 256 KB

  // 1) convert inputs to bf16 (single fused kernel)
  {
    const int na4 = SEQ * BATCH * EMB / 4;
    const int nb4 = 3 * EMB * EMB / 4;
    const int nc4 = EMB * EMB / 4;
    const int nblk = (na4 + nb4 + nc4 + 255) / 256;
    cvt3_f32_bf16<<<nblk, 256, 0, stream>>>(x, na4, w_qkv, nb4, w_out, nc4,
                                            x_bf, wqkv_bf, wout_bf);
  }

  // 2) QKV projection, scatter to Q (pre-scaled) / K [B][H][S][D] + V^T [B][H][D][S]
  gemm_bt<1><<<dim3(SEQ * BATCH / 128, 3 * EMB / 128), 256, 0, stream>>>(
      x_bf, wqkv_bf, b_qkv, nullptr, Qbuf, Kbuf, VTbuf, SEQ * BATCH, 3 * EMB, EMB);

  // 3) attention core (v9: 2 tiles per barrier)
  attn1<<<512, 256, 0, stream>>>(Qbuf, Kbuf, VTbuf, attn_bf, lbuf);

  // 4) attention average over heads (v8, frozen known-good)
  attn2<<<dim3(SEQ / 256, SEQ / 64, BATCH), 256, 0, stream>>>(Qbuf, Kbuf, lbuf, avg);

  // 5) output projection -> d_out
  gemm_bt<0><<<dim3(SEQ * BATCH / 128, EMB / 128), 256, 0, stream>>>(
      attn_bf, wout_bf, b_out, out, nullptr, nullptr, nullptr, SEQ * BATCH, EMB, EMB);
}